// Round 1
// 506.500 us; speedup vs baseline: 1.1337x; 1.1337x over previous
//
#include <hip/hip_runtime.h>
#include <math.h>

#define BATCH 512
#define SEQL  100
#define DIM   128
#define NITEMS 100000
#define NEGV  -1000000000.0f

// ---- workspace layout (float offsets) ----
#define OFF_WINT   98304     // 128x128  [k*128+j]
#define OFF_WOUTT  114688
#define OFF_WREADT 131072    // 384x128  [j*128+i]
#define OFF_HREAD  180224    // 512x128
#define OFF_DEG    245760    // 512x100
#define OFF_XIN    296960    // 51200x128 (dead after k_gru -> reused for apack)
#define OFF_HOUT   6850560   // 51200x128 (later holds H)
// ---- int offsets (in ints from ws base) ----
#define OFF_NODES_I 13404160 // 512x100 tokens (padded with 0)
#define OFF_SRC_I   13455360 // 512x99
#define OFF_DST_I   13506048 // 512x99
#define OFF_INFO_I  13556736 // 512x4: ecnt, li, flag(cnt>=2), n_nodes
// packed GRU weights (bf16 hi/lo MFMA fragments), float offset
#define OFF_WPACK_F 13558784 // 196608 halves = 98304 floats

typedef __attribute__((ext_vector_type(8))) short bf16x8;
typedef __attribute__((ext_vector_type(4))) short s16x4;
typedef __attribute__((ext_vector_type(4))) float f32x4;

__device__ __forceinline__ unsigned short bf16_rne(float x) {
  unsigned int u = __float_as_uint(x);
  unsigned int r = u + 0x7FFFu + ((u >> 16) & 1u);
  return (unsigned short)(r >> 16);
}
__device__ __forceinline__ float bf16_to_f(unsigned short h) {
  return __uint_as_float(((unsigned int)h) << 16);
}

// ------------------------------------------------------------------
// K0: transpose weights into ws + pack w_ih/w_hh as bf16 hi/lo MFMA B-frags.
// wpack layout: [mat(2)][n_tile(24)][k_chunk(4)][hi/lo(2)][lane(64)][8 halves]
// B-frag content: lane(quad,n) holds W[n_tile*16+n][k_chunk*32+quad*8+j], j=0..7
__global__ void k_prep(const float* __restrict__ w_ih, const float* __restrict__ w_hh,
                       const float* __restrict__ W_in, const float* __restrict__ W_out,
                       const float* __restrict__ W_read, float* __restrict__ ws,
                       unsigned short* __restrict__ wpack) {
  int idx = blockIdx.x * 256 + threadIdx.x;
  if (idx < 98304) {
    int mat = idx / 49152, rem = idx % 49152;
    int n = rem / 128, k = rem % 128;
    float v = (mat ? w_hh : w_ih)[rem];          // (384,128) row-major
    unsigned short hi = bf16_rne(v);
    unsigned short lo = bf16_rne(v - bf16_to_f(hi));
    int nt = n >> 4, nn = n & 15, c = k >> 5, quad = (k >> 3) & 3, j = k & 7;
    int lane = quad * 16 + nn;
    size_t base = ((size_t)((mat * 24 + nt) * 4 + c)) * 1024 + (size_t)lane * 8 + j;
    wpack[base] = hi;
    wpack[base + 512] = lo;
  }
  if (idx < 49152) {
    int i = idx / 384, jj = idx % 384;           // W_read is (128,384) row-major
    ws[OFF_WREADT + jj * 128 + i] = W_read[idx];
  }
  if (idx < 16384) {
    int j = idx / 128, k = idx % 128;            // W_in/W_out (128,128)
    ws[OFF_WINT  + k * 128 + j] = W_in[idx];
    ws[OFF_WOUTT + k * 128 + j] = W_out[idx];
  }
}

// ------------------------------------------------------------------
// K1: per-sample dedup + edges + deg.  grid=512, block=128
__global__ void k_build(const int* __restrict__ x, int* __restrict__ nodes,
                        float* __restrict__ deg, int* __restrict__ esrc,
                        int* __restrict__ edst, int* __restrict__ info) {
  int b = blockIdx.x, tid = threadIdx.x;
  __shared__ int sseq[SEQL];
  __shared__ int sfo[SEQL];
  __shared__ unsigned char sisf[SEQL];
  __shared__ int srank[SEQL];
  __shared__ int spos[SEQL];
  __shared__ int scinv[SEQL];
  __shared__ float sdeg[SEQL];
  __shared__ int s_nn, s_cnt;

  if (tid < SEQL) sseq[tid] = x[b * SEQL + tid];
  __syncthreads();
  int t = (tid < SEQL) ? sseq[tid] : 0;
  bool valid = (tid < SEQL) && (t != 0);
  int f = tid;
  if (valid) {
    for (int j = 0; j < tid; ++j) {
      if (sseq[j] == t) { f = j; break; }
    }
  }
  if (tid < SEQL) {
    sfo[tid] = f;
    sisf[tid] = (valid && f == tid) ? 1 : 0;
    sdeg[tid] = 0.f;
  }
  __syncthreads();
  if (tid == 0) {
    int nn = 0, c = 0;
    for (int i = 0; i < SEQL; ++i) {
      srank[i] = nn; nn += sisf[i];
      spos[i] = c;  c += (sseq[i] != 0) ? 1 : 0;
    }
    s_nn = nn; s_cnt = c;
  }
  __syncthreads();
  int nn = s_nn, cnt = s_cnt;
  if (valid) scinv[spos[tid]] = srank[sfo[tid]];
  __syncthreads();
  if (tid < SEQL) {
    if (sisf[tid]) nodes[b * SEQL + srank[tid]] = t;
    if (tid >= nn) nodes[b * SEQL + tid] = 0;     // pad -> emb[0]==0
  }
  __syncthreads();
  if (tid == 0) {
    int ec = (cnt >= 2) ? cnt - 1 : 0;
    for (int e = 0; e < ec; ++e) {
      int s = scinv[e], dnode = scinv[e + 1];
      esrc[b * 99 + e] = s;
      edst[b * 99 + e] = dnode;
      sdeg[dnode] += 1.f;
    }
    info[b * 4 + 0] = ec;
    info[b * 4 + 1] = (cnt >= 1) ? scinv[cnt - 1] : 0;
    info[b * 4 + 2] = (cnt >= 2) ? 1 : 0;
    info[b * 4 + 3] = nn;
  }
  __syncthreads();
  if (tid < SEQL) deg[b * SEQL + tid] = fmaxf(sdeg[tid], 1.f);
}

// ------------------------------------------------------------------
// K2: XIN = gather(emb) @ W_inT ; HOUT = gather(emb) @ W_outT
__global__ __launch_bounds__(256) void k_gemm_inout(
    const float* __restrict__ emb, const float* __restrict__ ws,
    const int* __restrict__ nodes, float* __restrict__ xin, float* __restrict__ hout) {
  __shared__ float Xs[64 * 128];
  int tid = threadIdx.x;
  int rowbase = blockIdx.x * 64;
  const float4* emb4 = (const float4*)emb;
  float4* Xs4 = (float4*)Xs;
  for (int e = tid; e < 64 * 32; e += 256) {
    int r = e >> 5, c4 = e & 31;
    int tok = nodes[rowbase + r];
    Xs4[e] = emb4[(size_t)tok * 32 + c4];
  }
  __syncthreads();
  int jt = tid & 31;
  int rt = tid >> 5;
  const float4* Wi4 = (const float4*)(ws + OFF_WINT);
  const float4* Wo4 = (const float4*)(ws + OFF_WOUTT);
  float accI[8][4]; float accO[8][4];
  #pragma unroll
  for (int r = 0; r < 8; ++r)
    #pragma unroll
    for (int j = 0; j < 4; ++j) { accI[r][j] = 0.f; accO[r][j] = 0.f; }

  for (int k0 = 0; k0 < 128; k0 += 4) {
    float wi[4][4], wo[4][4];
    #pragma unroll
    for (int kk = 0; kk < 4; ++kk) {
      float4 a = Wi4[(k0 + kk) * 32 + jt];
      wi[kk][0] = a.x; wi[kk][1] = a.y; wi[kk][2] = a.z; wi[kk][3] = a.w;
      float4 o = Wo4[(k0 + kk) * 32 + jt];
      wo[kk][0] = o.x; wo[kk][1] = o.y; wo[kk][2] = o.z; wo[kk][3] = o.w;
    }
    #pragma unroll
    for (int r = 0; r < 8; ++r) {
      float4 xv4 = Xs4[(rt * 8 + r) * 32 + (k0 >> 2)];
      float xv[4] = {xv4.x, xv4.y, xv4.z, xv4.w};
      #pragma unroll
      for (int kk = 0; kk < 4; ++kk)
        #pragma unroll
        for (int jj = 0; jj < 4; ++jj) {
          accI[r][jj] = fmaf(xv[kk], wi[kk][jj], accI[r][jj]);
          accO[r][jj] = fmaf(xv[kk], wo[kk][jj], accO[r][jj]);
        }
    }
  }
  float4* xin4 = (float4*)xin;
  float4* hout4 = (float4*)hout;
  #pragma unroll
  for (int r = 0; r < 8; ++r) {
    int row = rowbase + rt * 8 + r;
    float4 vI = {accI[r][0], accI[r][1], accI[r][2], accI[r][3]};
    float4 vO = {accO[r][0], accO[r][1], accO[r][2], accO[r][3]};
    xin4[(size_t)row * 32 + jt] = vI;
    hout4[(size_t)row * 32 + jt] = vO;
  }
}

// ------------------------------------------------------------------
// K3: XIN[dst] += HOUT[src]/deg[dst] per edge.
__global__ void k_scatter(const float* __restrict__ hout, float* __restrict__ xin,
                          const float* __restrict__ deg, const int* __restrict__ esrc,
                          const int* __restrict__ edst, const int* __restrict__ info) {
  int b = blockIdx.x, k = threadIdx.x;
  __shared__ float agg[SEQL * DIM];
  for (int n = 0; n < SEQL; ++n) agg[n * DIM + k] = 0.f;
  int ec = info[b * 4 + 0];
  for (int e = 0; e < ec; ++e) {
    int s = esrc[b * 99 + e], dn = edst[b * 99 + e];
    agg[dn * DIM + k] += hout[((size_t)(b * SEQL + s)) * DIM + k];
  }
  for (int n = 0; n < SEQL; ++n) {
    float dg = deg[b * SEQL + n];
    size_t idx = ((size_t)(b * SEQL + n)) * DIM + k;
    xin[idx] += agg[n * DIM + k] / dg;
  }
}

// ------------------------------------------------------------------
// K4 v3: split-bf16 MFMA GRU.  grid=1600 (32 rows/block), block=128 (2 waves).
// Each wave: one 16-row m-tile, all 384 gi/gh cols via 16x16x32 MFMA,
// 3-term split (hi*hi + hi*lo + lo*hi) for ~fp32 accuracy.
#define GPAD 136
__global__ __launch_bounds__(128) void k_gru(
    const float* __restrict__ emb, const int* __restrict__ nodes,
    const unsigned short* __restrict__ wpack, const float* __restrict__ xin,
    const float* __restrict__ b_ih, const float* __restrict__ b_hh,
    const int* __restrict__ info, float* __restrict__ Hbuf) {
  __shared__ unsigned short Xhi[32 * GPAD];
  __shared__ unsigned short Xlo[32 * GPAD];
  __shared__ unsigned short Hhi[32 * GPAD];
  __shared__ unsigned short Hlo[32 * GPAD];
  int tid = threadIdx.x;
  int rowbase = blockIdx.x * 32;
  const float4* emb4 = (const float4*)emb;
  const float4* xin4 = (const float4*)xin;
  for (int e = tid; e < 32 * 32; e += 128) {
    int r = e >> 5, c4 = e & 31;
    int row = rowbase + r;
    float4 xv = xin4[(size_t)row * 32 + c4];
    int tok = nodes[row];
    float4 hv = emb4[(size_t)tok * 32 + c4];
    int base = r * GPAD + c4 * 4;
    float xs[4] = {xv.x, xv.y, xv.z, xv.w};
    float hs[4] = {hv.x, hv.y, hv.z, hv.w};
    #pragma unroll
    for (int q = 0; q < 4; ++q) {
      unsigned short xh = bf16_rne(xs[q]);
      Xhi[base + q] = xh; Xlo[base + q] = bf16_rne(xs[q] - bf16_to_f(xh));
      unsigned short hh = bf16_rne(hs[q]);
      Hhi[base + q] = hh; Hlo[base + q] = bf16_rne(hs[q] - bf16_to_f(hh));
    }
  }
  __syncthreads();
  int wave = tid >> 6, lane = tid & 63;
  int quad = lane >> 4, nIdx = lane & 15;
  int mrow = wave * 16 + nIdx;           // A-frag row (m = lane&15)
  bf16x8 aXh[4], aXl[4], aHh[4], aHl[4];
  #pragma unroll
  for (int c = 0; c < 4; ++c) {
    int off = mrow * GPAD + c * 32 + quad * 8;   // 16B-aligned (GPAD*2 % 16 == 0)
    aXh[c] = *(const bf16x8*)&Xhi[off];
    aXl[c] = *(const bf16x8*)&Xlo[off];
    aHh[c] = *(const bf16x8*)&Hhi[off];
    aHl[c] = *(const bf16x8*)&Hlo[off];
  }
  int grows[4]; int zm[4];
  #pragma unroll
  for (int i = 0; i < 4; ++i) {
    int grow = rowbase + wave * 16 + quad * 4 + i;
    grows[i] = grow;
    int bs = grow / SEQL;
    int n = grow - bs * SEQL;
    zm[i] = (n < info[bs * 4 + 3]) ? 1 : 0;
  }

  for (int t = 0; t < 8; ++t) {
    f32x4 acc[3][2];                     // [gate r/z/n][gi/gh]
    #pragma unroll
    for (int g = 0; g < 3; ++g)
      #pragma unroll
      for (int m = 0; m < 2; ++m) acc[g][m] = (f32x4){0.f, 0.f, 0.f, 0.f};

    for (int c = 0; c < 4; ++c) {
      bf16x8 Bh[3][2], Bl[3][2];
      #pragma unroll
      for (int g = 0; g < 3; ++g) {
        int nt = g * 8 + t;
        #pragma unroll
        for (int m = 0; m < 2; ++m) {
          size_t bidx = (size_t)((m * 24 + nt) * 4 + c) * 1024 + (size_t)lane * 8;
          Bh[g][m] = *(const bf16x8*)&wpack[bidx];
          Bl[g][m] = *(const bf16x8*)&wpack[bidx + 512];
        }
      }
      // split-major ordering: same acc touched every 6 MFMAs
      #pragma unroll
      for (int g = 0; g < 3; ++g) {
        acc[g][0] = __builtin_amdgcn_mfma_f32_16x16x32_bf16(aXh[c], Bh[g][0], acc[g][0], 0, 0, 0);
        acc[g][1] = __builtin_amdgcn_mfma_f32_16x16x32_bf16(aHh[c], Bh[g][1], acc[g][1], 0, 0, 0);
      }
      #pragma unroll
      for (int g = 0; g < 3; ++g) {
        acc[g][0] = __builtin_amdgcn_mfma_f32_16x16x32_bf16(aXh[c], Bl[g][0], acc[g][0], 0, 0, 0);
        acc[g][1] = __builtin_amdgcn_mfma_f32_16x16x32_bf16(aHh[c], Bl[g][1], acc[g][1], 0, 0, 0);
      }
      #pragma unroll
      for (int g = 0; g < 3; ++g) {
        acc[g][0] = __builtin_amdgcn_mfma_f32_16x16x32_bf16(aXl[c], Bh[g][0], acc[g][0], 0, 0, 0);
        acc[g][1] = __builtin_amdgcn_mfma_f32_16x16x32_bf16(aHl[c], Bh[g][1], acc[g][1], 0, 0, 0);
      }
    }
    int j = t * 16 + nIdx;
    float biR = b_ih[j],       bhR = b_hh[j];
    float biZ = b_ih[128 + j], bhZ = b_hh[128 + j];
    float biN = b_ih[256 + j], bhN = b_hh[256 + j];
    #pragma unroll
    for (int i = 0; i < 4; ++i) {
      float gr = acc[0][0][i] + biR + acc[0][1][i] + bhR;
      float gz = acc[1][0][i] + biZ + acc[1][1][i] + bhZ;
      float r = 1.f / (1.f + expf(-gr));
      float z = 1.f / (1.f + expf(-gz));
      float nct = tanhf(acc[2][0][i] + biN + r * (acc[2][1][i] + bhN));
      int lrow = wave * 16 + quad * 4 + i;
      float h0 = bf16_to_f(Hhi[lrow * GPAD + j]) + bf16_to_f(Hlo[lrow * GPAD + j]);
      float h = (1.f - z) * nct + z * h0;
      if (!zm[i]) h = 0.f;
      Hbuf[(size_t)grows[i] * 128 + j] = h;
    }
  }
}

// ------------------------------------------------------------------
// K5: attention + h_read.  grid=512, block=128
#define HLS 129
__global__ void k_attn(const float* __restrict__ Hbuf, const float* __restrict__ ws,
                       const float* __restrict__ b_read, const int* __restrict__ info,
                       float* __restrict__ hread) {
  int b = blockIdx.x, tid = threadIdx.x;
  __shared__ float Hl[SEQL * HLS];
  __shared__ float sc[128];
  __shared__ float hl[128];
  __shared__ float att[SEQL];
  __shared__ float loc[128];
  int nn = info[b * 4 + 3], li = info[b * 4 + 1];
  for (int e = tid; e < SEQL * 128; e += 128) {
    int r = e >> 7, k = e & 127;
    Hl[r * HLS + k] = Hbuf[((size_t)(b * SEQL + r)) * DIM + k];
  }
  __syncthreads();
  hl[tid] = Hl[li * HLS + tid];
  __syncthreads();
  float scr = NEGV;
  if (tid < nn) {
    float s = 0.f;
    for (int k = 0; k < 128; ++k) s += Hl[tid * HLS + k] * hl[k];
    scr = s;
  }
  sc[tid] = scr;
  __syncthreads();
  if (tid == 0) {
    float m = sc[0];
    for (int n = 1; n < SEQL; ++n) m = fmaxf(m, sc[n]);
    float sum = 0.f;
    for (int n = 0; n < SEQL; ++n) { float e = expf(sc[n] - m); att[n] = e; sum += e; }
    float inv = 1.f / sum;
    for (int n = 0; n < SEQL; ++n) att[n] *= inv;
  }
  __syncthreads();
  float lv = 0.f;
  for (int n = 0; n < SEQL; ++n) lv = fmaf(att[n], Hl[n * HLS + tid], lv);
  loc[tid] = lv;
  __syncthreads();
  const float* WrT = ws + OFF_WREADT;
  float acc = b_read[tid];
  for (int j = 0; j < 128; ++j) acc = fmaf(WrT[j * 128 + tid], hl[j], acc);
  for (int j = 0; j < 128; ++j) acc = fmaf(WrT[(128 + j) * 128 + tid], loc[j], acc);
  hread[b * 128 + tid] = tanhf(acc);
}

// ------------------------------------------------------------------
// K5b: pack hread (512x128) into bf16 hi/lo A-fragments for k_out.
// apack layout: [mtile(32)][kc(4)][hi/lo(2)][lane(64)][8 halves]
// A-frag: lane(quad,rr) holds hread[mt*16+rr][kc*32+quad*8+j], j=0..7
__global__ __launch_bounds__(256) void k_packA(
    const float* __restrict__ hread, unsigned short* __restrict__ apack) {
  int idx = blockIdx.x * 256 + threadIdx.x;     // 8192 slots total
  if (idx >= 8192) return;
  int lane = idx & 63;
  int kc = (idx >> 6) & 3;
  int mt = idx >> 8;
  int quad = lane >> 4, rr = lane & 15;
  int row = mt * 16 + rr;
  int kbase = kc * 32 + quad * 8;
  const float4* hr4 = (const float4*)(hread + row * 128 + kbase);
  float4 v0 = hr4[0], v1 = hr4[1];
  float vs[8] = {v0.x, v0.y, v0.z, v0.w, v1.x, v1.y, v1.z, v1.w};
  bf16x8 hi, lo;
  #pragma unroll
  for (int j = 0; j < 8; ++j) {
    unsigned short h = bf16_rne(vs[j]);
    hi[j] = (short)h;
    lo[j] = (short)bf16_rne(vs[j] - bf16_to_f(h));
  }
  size_t base = ((size_t)(mt * 4 + kc) * 2) * 512 + (size_t)lane * 8;
  *(bf16x8*)&apack[base] = hi;
  *(bf16x8*)&apack[base + 512] = lo;
}

// ------------------------------------------------------------------
// K6 v3: out = h_read @ emb^T via 3-term split-bf16 MFMA.
// grid (4, 1563): block = 128 batch rows x 64 items, 256 thr = 4 waves.
// Wave w: 2 m-tiles (32 batch rows) x 4 n-tiles (64 items).
// emb tile converted to hi/lo bf16 in LDS, pitch 136 halves (2-way bank alias = free).
#define EPITCH 136
__global__ __launch_bounds__(256) void k_out(
    const float* __restrict__ emb, const unsigned short* __restrict__ apack,
    const int* __restrict__ info, float* __restrict__ out) {
  __shared__ unsigned short Ehi[64 * EPITCH];
  __shared__ unsigned short Elo[64 * EPITCH];
  int tid = threadIdx.x;
  int b0  = blockIdx.x * 128;
  int it0 = blockIdx.y * 64;

  // ---- load 64x128 emb tile (fp32) and convert to hi/lo bf16 in LDS ----
  const float4* emb4 = (const float4*)emb;
  #pragma unroll
  for (int s = 0; s < 8; ++s) {
    int idx = s * 256 + tid;            // 0..2047 ; 32 float4 per row
    int r = idx >> 5, c4 = idx & 31;
    int item = it0 + r;
    float4 v = (item < NITEMS) ? emb4[(size_t)item * 32 + c4]
                               : (float4){0.f, 0.f, 0.f, 0.f};
    float vs[4] = {v.x, v.y, v.z, v.w};
    s16x4 hv, lv;
    #pragma unroll
    for (int q = 0; q < 4; ++q) {
      unsigned short h = bf16_rne(vs[q]);
      hv[q] = (short)h;
      lv[q] = (short)bf16_rne(vs[q] - bf16_to_f(h));
    }
    int base = r * EPITCH + c4 * 4;     // 8B-aligned (EPITCH*2 % 8 == 0)
    *(s16x4*)&Ehi[base] = hv;
    *(s16x4*)&Elo[base] = lv;
  }
  __syncthreads();

  int wave = tid >> 6, lane = tid & 63;
  int quad = lane >> 4, nIdx = lane & 15;
  int mtg0 = blockIdx.x * 8 + wave * 2;   // global m-tile (of 32)

  // A-frags from packed hread (L2-resident, fully coalesced 16B/lane)
  bf16x8 ah[2][4], al[2][4];
  #pragma unroll
  for (int m2 = 0; m2 < 2; ++m2)
    #pragma unroll
    for (int kc = 0; kc < 4; ++kc) {
      size_t base = ((size_t)((mtg0 + m2) * 4 + kc) * 2) * 512 + (size_t)lane * 8;
      ah[m2][kc] = *(const bf16x8*)&apack[base];
      al[m2][kc] = *(const bf16x8*)&apack[base + 512];
    }

  f32x4 acc[2][4];
  #pragma unroll
  for (int m2 = 0; m2 < 2; ++m2)
    #pragma unroll
    for (int nt = 0; nt < 4; ++nt) acc[m2][nt] = (f32x4){0.f, 0.f, 0.f, 0.f};

  #pragma unroll
  for (int nt = 0; nt < 4; ++nt) {
    int eoff = (nt * 16 + nIdx) * EPITCH + quad * 8;  // 16B-aligned
    #pragma unroll
    for (int kc = 0; kc < 4; ++kc) {
      bf16x8 Bh = *(const bf16x8*)&Ehi[eoff + kc * 32];
      bf16x8 Bl = *(const bf16x8*)&Elo[eoff + kc * 32];
      acc[0][nt] = __builtin_amdgcn_mfma_f32_16x16x32_bf16(ah[0][kc], Bh, acc[0][nt], 0, 0, 0);
      acc[1][nt] = __builtin_amdgcn_mfma_f32_16x16x32_bf16(ah[1][kc], Bh, acc[1][nt], 0, 0, 0);
      acc[0][nt] = __builtin_amdgcn_mfma_f32_16x16x32_bf16(al[0][kc], Bh, acc[0][nt], 0, 0, 0);
      acc[1][nt] = __builtin_amdgcn_mfma_f32_16x16x32_bf16(al[1][kc], Bh, acc[1][nt], 0, 0, 0);
      acc[0][nt] = __builtin_amdgcn_mfma_f32_16x16x32_bf16(ah[0][kc], Bl, acc[0][nt], 0, 0, 0);
      acc[1][nt] = __builtin_amdgcn_mfma_f32_16x16x32_bf16(ah[1][kc], Bl, acc[1][nt], 0, 0, 0);
    }
  }

  // ---- epilogue: C layout col=lane&15, row=(lane>>4)*4+i ----
  int flags[2][4];
  #pragma unroll
  for (int m2 = 0; m2 < 2; ++m2)
    #pragma unroll
    for (int i = 0; i < 4; ++i) {
      int b = b0 + (wave * 2 + m2) * 16 + quad * 4 + i;
      flags[m2][i] = info[b * 4 + 2];
    }
  #pragma unroll
  for (int m2 = 0; m2 < 2; ++m2)
    #pragma unroll
    for (int nt = 0; nt < 4; ++nt) {
      int item = it0 + nt * 16 + nIdx;
      #pragma unroll
      for (int i = 0; i < 4; ++i) {
        int b = b0 + (wave * 2 + m2) * 16 + quad * 4 + i;
        float v = flags[m2][i] ? acc[m2][nt][i]
                               : ((item == 0) ? 0.f : NEGV);
        if (item < NITEMS) out[(size_t)b * NITEMS + item] = v;
      }
    }
}

// ------------------------------------------------------------------
extern "C" void kernel_launch(void* const* d_in, const int* in_sizes, int n_in,
                              void* d_out, int out_size, void* d_ws, size_t ws_size,
                              hipStream_t stream) {
  const int*   x      = (const int*)d_in[0];
  const float* emb    = (const float*)d_in[2];
  const float* W_in   = (const float*)d_in[3];
  const float* W_out  = (const float*)d_in[4];
  const float* w_ih   = (const float*)d_in[5];
  const float* w_hh   = (const float*)d_in[6];
  const float* b_ih   = (const float*)d_in[7];
  const float* b_hh   = (const float*)d_in[8];
  const float* W_read = (const float*)d_in[9];
  const float* b_read = (const float*)d_in[10];
  float* ws  = (float*)d_ws;
  int*   wsi = (int*)d_ws;
  unsigned short* wpack = (unsigned short*)(ws + OFF_WPACK_F);
  unsigned short* apack = (unsigned short*)(ws + OFF_XIN);  // xin dead after k_gru
  float* out = (float*)d_out;

  k_prep<<<384, 256, 0, stream>>>(w_ih, w_hh, W_in, W_out, W_read, ws, wpack);
  k_build<<<BATCH, 128, 0, stream>>>(x, wsi + OFF_NODES_I, ws + OFF_DEG,
                                     wsi + OFF_SRC_I, wsi + OFF_DST_I, wsi + OFF_INFO_I);
  k_gemm_inout<<<800, 256, 0, stream>>>(emb, ws, wsi + OFF_NODES_I,
                                        ws + OFF_XIN, ws + OFF_HOUT);
  k_scatter<<<BATCH, 128, 0, stream>>>(ws + OFF_HOUT, ws + OFF_XIN, ws + OFF_DEG,
                                       wsi + OFF_SRC_I, wsi + OFF_DST_I, wsi + OFF_INFO_I);
  k_gru<<<1600, 128, 0, stream>>>(emb, wsi + OFF_NODES_I, wpack, ws + OFF_XIN,
                                  b_ih, b_hh, wsi + OFF_INFO_I, ws + OFF_HOUT);
  k_attn<<<BATCH, 128, 0, stream>>>(ws + OFF_HOUT, ws, b_read, wsi + OFF_INFO_I,
                                    ws + OFF_HREAD);
  k_packA<<<32, 256, 0, stream>>>(ws + OFF_HREAD, apack);
  k_out<<<dim3(4, 1563), 256, 0, stream>>>(emb, apack, wsi + OFF_INFO_I, out);
}

// Round 2
// 473.491 us; speedup vs baseline: 1.2128x; 1.0697x over previous
//
#include <hip/hip_runtime.h>
#include <math.h>

#define BATCH 512
#define SEQL  100
#define DIM   128
#define NITEMS 100000
#define NEGV  -1000000000.0f

// ---- workspace layout (float offsets) ----
// 0 .. 32768: wpack2 (W_in/W_out bf16 hi/lo B-frags, 65536 halves)
#define OFF_WREADT 131072    // 384x128  [j*128+i]
#define OFF_HREAD  180224    // 512x128
#define OFF_DEG    245760    // 512x100
#define OFF_XIN    296960    // 51200x128 (dead after k_gru -> reused for apack)
#define OFF_HOUT   6850560   // 51200x128 (later holds H; dead after k_attn)
#define OFF_EPACK_F (OFF_XIN + 131072)  // 12804096 floats; overlaps XIN+HOUT tails,
                                        // written by k_epack AFTER k_attn only.
// ---- int offsets (in ints from ws base) ----
#define OFF_NODES_I 13404160 // 512x100 tokens (padded with 0)
#define OFF_SRC_I   13455360 // 512x99
#define OFF_DST_I   13506048 // 512x99
#define OFF_INFO_I  13556736 // 512x4: ecnt, li, flag(cnt>=2), n_nodes
// packed GRU weights (bf16 hi/lo MFMA fragments), float offset
#define OFF_WPACK_F 13558784 // 196608 halves = 98304 floats

typedef __attribute__((ext_vector_type(8))) short bf16x8;
typedef __attribute__((ext_vector_type(4))) short s16x4;
typedef __attribute__((ext_vector_type(4))) float f32x4;

__device__ __forceinline__ unsigned short bf16_rne(float x) {
  unsigned int u = __float_as_uint(x);
  unsigned int r = u + 0x7FFFu + ((u >> 16) & 1u);
  return (unsigned short)(r >> 16);
}
__device__ __forceinline__ float bf16_to_f(unsigned short h) {
  return __uint_as_float(((unsigned int)h) << 16);
}

// ------------------------------------------------------------------
// K0: pack w_ih/w_hh (wpack), W_in/W_out (wpack2) as bf16 hi/lo MFMA frags;
// transpose W_read.
// frag rule: lane(quad,n) holds W[tile*16+n][chunk*32+quad*8+j], j=0..7
__global__ void k_prep(const float* __restrict__ w_ih, const float* __restrict__ w_hh,
                       const float* __restrict__ W_in, const float* __restrict__ W_out,
                       const float* __restrict__ W_read, float* __restrict__ ws,
                       unsigned short* __restrict__ wpack) {
  int idx = blockIdx.x * 256 + threadIdx.x;
  if (idx < 98304) {
    int mat = idx / 49152, rem = idx % 49152;
    int n = rem / 128, k = rem % 128;
    float v = (mat ? w_hh : w_ih)[rem];          // (384,128) row-major
    unsigned short hi = bf16_rne(v);
    unsigned short lo = bf16_rne(v - bf16_to_f(hi));
    int nt = n >> 4, nn = n & 15, c = k >> 5, quad = (k >> 3) & 3, j = k & 7;
    int lane = quad * 16 + nn;
    size_t base = ((size_t)((mat * 24 + nt) * 4 + c)) * 1024 + (size_t)lane * 8 + j;
    wpack[base] = hi;
    wpack[base + 512] = lo;
  }
  if (idx < 49152) {
    int i = idx / 384, jj = idx % 384;           // W_read is (128,384) row-major
    ws[OFF_WREADT + jj * 128 + i] = W_read[idx];
  }
  if (idx < 32768) {                             // W_in/W_out (128,128) -> wpack2
    int mat = idx >> 14, rem = idx & 16383;
    int n = rem >> 7, k = rem & 127;
    float v = (mat ? W_out : W_in)[rem];
    unsigned short hi = bf16_rne(v);
    unsigned short lo = bf16_rne(v - bf16_to_f(hi));
    int nt = n >> 4, nn = n & 15, c = k >> 5, quad = (k >> 3) & 3, j = k & 7;
    int lane = quad * 16 + nn;
    size_t base = ((size_t)((mat * 8 + nt) * 4 + c)) * 1024 + (size_t)lane * 8 + j;
    unsigned short* wpack2 = (unsigned short*)ws;
    wpack2[base] = hi;
    wpack2[base + 512] = lo;
  }
}

// ------------------------------------------------------------------
// K1: per-sample dedup + edges + deg.  grid=512, block=128
__global__ void k_build(const int* __restrict__ x, int* __restrict__ nodes,
                        float* __restrict__ deg, int* __restrict__ esrc,
                        int* __restrict__ edst, int* __restrict__ info) {
  int b = blockIdx.x, tid = threadIdx.x;
  __shared__ int sseq[SEQL];
  __shared__ int sfo[SEQL];
  __shared__ unsigned char sisf[SEQL];
  __shared__ int srank[SEQL];
  __shared__ int spos[SEQL];
  __shared__ int scinv[SEQL];
  __shared__ float sdeg[SEQL];
  __shared__ int s_nn, s_cnt;

  if (tid < SEQL) sseq[tid] = x[b * SEQL + tid];
  __syncthreads();
  int t = (tid < SEQL) ? sseq[tid] : 0;
  bool valid = (tid < SEQL) && (t != 0);
  int f = tid;
  if (valid) {
    for (int j = 0; j < tid; ++j) {
      if (sseq[j] == t) { f = j; break; }
    }
  }
  if (tid < SEQL) {
    sfo[tid] = f;
    sisf[tid] = (valid && f == tid) ? 1 : 0;
    sdeg[tid] = 0.f;
  }
  __syncthreads();
  if (tid == 0) {
    int nn = 0, c = 0;
    for (int i = 0; i < SEQL; ++i) {
      srank[i] = nn; nn += sisf[i];
      spos[i] = c;  c += (sseq[i] != 0) ? 1 : 0;
    }
    s_nn = nn; s_cnt = c;
  }
  __syncthreads();
  int nn = s_nn, cnt = s_cnt;
  if (valid) scinv[spos[tid]] = srank[sfo[tid]];
  __syncthreads();
  if (tid < SEQL) {
    if (sisf[tid]) nodes[b * SEQL + srank[tid]] = t;
    if (tid >= nn) nodes[b * SEQL + tid] = 0;     // pad -> emb[0]==0
  }
  __syncthreads();
  if (tid == 0) {
    int ec = (cnt >= 2) ? cnt - 1 : 0;
    for (int e = 0; e < ec; ++e) {
      int s = scinv[e], dnode = scinv[e + 1];
      esrc[b * 99 + e] = s;
      edst[b * 99 + e] = dnode;
      sdeg[dnode] += 1.f;
    }
    info[b * 4 + 0] = ec;
    info[b * 4 + 1] = (cnt >= 1) ? scinv[cnt - 1] : 0;
    info[b * 4 + 2] = (cnt >= 2) ? 1 : 0;
    info[b * 4 + 3] = nn;
  }
  __syncthreads();
  if (tid < SEQL) deg[b * SEQL + tid] = fmaxf(sdeg[tid], 1.f);
}

// ------------------------------------------------------------------
// K2 v2: XIN = gather(emb) @ W_inT ; HOUT = gather(emb) @ W_outT
// split-bf16 MFMA, same structure as k_gru.  grid=1600 (32 rows), block=128.
#define GPAD 136
__global__ __launch_bounds__(128) void k_gemm_inout(
    const float* __restrict__ emb, const unsigned short* __restrict__ wpack2,
    const int* __restrict__ nodes, float* __restrict__ xin, float* __restrict__ hout) {
  __shared__ unsigned short Hhi[32 * GPAD];
  __shared__ unsigned short Hlo[32 * GPAD];
  int tid = threadIdx.x;
  int rowbase = blockIdx.x * 32;
  const float4* emb4 = (const float4*)emb;
  for (int e = tid; e < 32 * 32; e += 128) {
    int r = e >> 5, c4 = e & 31;
    int tok = nodes[rowbase + r];
    float4 hv = emb4[(size_t)tok * 32 + c4];
    int base = r * GPAD + c4 * 4;
    float hs[4] = {hv.x, hv.y, hv.z, hv.w};
    #pragma unroll
    for (int q = 0; q < 4; ++q) {
      unsigned short hh = bf16_rne(hs[q]);
      Hhi[base + q] = hh;
      Hlo[base + q] = bf16_rne(hs[q] - bf16_to_f(hh));
    }
  }
  __syncthreads();
  int wave = tid >> 6, lane = tid & 63;
  int quad = lane >> 4, nIdx = lane & 15;
  int mrow = wave * 16 + nIdx;
  bf16x8 aH[4], aL[4];
  #pragma unroll
  for (int c = 0; c < 4; ++c) {
    int off = mrow * GPAD + c * 32 + quad * 8;
    aH[c] = *(const bf16x8*)&Hhi[off];
    aL[c] = *(const bf16x8*)&Hlo[off];
  }
  for (int t = 0; t < 8; ++t) {
    f32x4 accI = (f32x4){0.f, 0.f, 0.f, 0.f};
    f32x4 accO = (f32x4){0.f, 0.f, 0.f, 0.f};
    #pragma unroll
    for (int c = 0; c < 4; ++c) {
      size_t bi = ((size_t)((0 * 8 + t) * 4 + c)) * 1024 + (size_t)lane * 8;
      size_t bo = ((size_t)((1 * 8 + t) * 4 + c)) * 1024 + (size_t)lane * 8;
      bf16x8 BiH = *(const bf16x8*)&wpack2[bi];
      bf16x8 BiL = *(const bf16x8*)&wpack2[bi + 512];
      bf16x8 BoH = *(const bf16x8*)&wpack2[bo];
      bf16x8 BoL = *(const bf16x8*)&wpack2[bo + 512];
      accI = __builtin_amdgcn_mfma_f32_16x16x32_bf16(aH[c], BiH, accI, 0, 0, 0);
      accO = __builtin_amdgcn_mfma_f32_16x16x32_bf16(aH[c], BoH, accO, 0, 0, 0);
      accI = __builtin_amdgcn_mfma_f32_16x16x32_bf16(aL[c], BiH, accI, 0, 0, 0);
      accO = __builtin_amdgcn_mfma_f32_16x16x32_bf16(aL[c], BoH, accO, 0, 0, 0);
      accI = __builtin_amdgcn_mfma_f32_16x16x32_bf16(aH[c], BiL, accI, 0, 0, 0);
      accO = __builtin_amdgcn_mfma_f32_16x16x32_bf16(aH[c], BoL, accO, 0, 0, 0);
    }
    int j = t * 16 + nIdx;
    #pragma unroll
    for (int i = 0; i < 4; ++i) {
      size_t row = (size_t)(rowbase + wave * 16 + quad * 4 + i);
      xin[row * 128 + j]  = accI[i];
      hout[row * 128 + j] = accO[i];
    }
  }
}

// ------------------------------------------------------------------
// K3: XIN[dst] += HOUT[src]/deg[dst] per edge.
__global__ void k_scatter(const float* __restrict__ hout, float* __restrict__ xin,
                          const float* __restrict__ deg, const int* __restrict__ esrc,
                          const int* __restrict__ edst, const int* __restrict__ info) {
  int b = blockIdx.x, k = threadIdx.x;
  __shared__ float agg[SEQL * DIM];
  for (int n = 0; n < SEQL; ++n) agg[n * DIM + k] = 0.f;
  int ec = info[b * 4 + 0];
  for (int e = 0; e < ec; ++e) {
    int s = esrc[b * 99 + e], dn = edst[b * 99 + e];
    agg[dn * DIM + k] += hout[((size_t)(b * SEQL + s)) * DIM + k];
  }
  for (int n = 0; n < SEQL; ++n) {
    float dg = deg[b * SEQL + n];
    size_t idx = ((size_t)(b * SEQL + n)) * DIM + k;
    xin[idx] += agg[n * DIM + k] / dg;
  }
}

// ------------------------------------------------------------------
// K4: split-bf16 MFMA GRU.  grid=1600 (32 rows/block), block=128 (2 waves).
__global__ __launch_bounds__(128) void k_gru(
    const float* __restrict__ emb, const int* __restrict__ nodes,
    const unsigned short* __restrict__ wpack, const float* __restrict__ xin,
    const float* __restrict__ b_ih, const float* __restrict__ b_hh,
    const int* __restrict__ info, float* __restrict__ Hbuf) {
  __shared__ unsigned short Xhi[32 * GPAD];
  __shared__ unsigned short Xlo[32 * GPAD];
  __shared__ unsigned short Hhi[32 * GPAD];
  __shared__ unsigned short Hlo[32 * GPAD];
  int tid = threadIdx.x;
  int rowbase = blockIdx.x * 32;
  const float4* emb4 = (const float4*)emb;
  const float4* xin4 = (const float4*)xin;
  for (int e = tid; e < 32 * 32; e += 128) {
    int r = e >> 5, c4 = e & 31;
    int row = rowbase + r;
    float4 xv = xin4[(size_t)row * 32 + c4];
    int tok = nodes[row];
    float4 hv = emb4[(size_t)tok * 32 + c4];
    int base = r * GPAD + c4 * 4;
    float xs[4] = {xv.x, xv.y, xv.z, xv.w};
    float hs[4] = {hv.x, hv.y, hv.z, hv.w};
    #pragma unroll
    for (int q = 0; q < 4; ++q) {
      unsigned short xh = bf16_rne(xs[q]);
      Xhi[base + q] = xh; Xlo[base + q] = bf16_rne(xs[q] - bf16_to_f(xh));
      unsigned short hh = bf16_rne(hs[q]);
      Hhi[base + q] = hh; Hlo[base + q] = bf16_rne(hs[q] - bf16_to_f(hh));
    }
  }
  __syncthreads();
  int wave = tid >> 6, lane = tid & 63;
  int quad = lane >> 4, nIdx = lane & 15;
  int mrow = wave * 16 + nIdx;
  bf16x8 aXh[4], aXl[4], aHh[4], aHl[4];
  #pragma unroll
  for (int c = 0; c < 4; ++c) {
    int off = mrow * GPAD + c * 32 + quad * 8;
    aXh[c] = *(const bf16x8*)&Xhi[off];
    aXl[c] = *(const bf16x8*)&Xlo[off];
    aHh[c] = *(const bf16x8*)&Hhi[off];
    aHl[c] = *(const bf16x8*)&Hlo[off];
  }
  int grows[4]; int zm[4];
  #pragma unroll
  for (int i = 0; i < 4; ++i) {
    int grow = rowbase + wave * 16 + quad * 4 + i;
    grows[i] = grow;
    int bs = grow / SEQL;
    int n = grow - bs * SEQL;
    zm[i] = (n < info[bs * 4 + 3]) ? 1 : 0;
  }

  for (int t = 0; t < 8; ++t) {
    f32x4 acc[3][2];
    #pragma unroll
    for (int g = 0; g < 3; ++g)
      #pragma unroll
      for (int m = 0; m < 2; ++m) acc[g][m] = (f32x4){0.f, 0.f, 0.f, 0.f};

    for (int c = 0; c < 4; ++c) {
      bf16x8 Bh[3][2], Bl[3][2];
      #pragma unroll
      for (int g = 0; g < 3; ++g) {
        int nt = g * 8 + t;
        #pragma unroll
        for (int m = 0; m < 2; ++m) {
          size_t bidx = (size_t)((m * 24 + nt) * 4 + c) * 1024 + (size_t)lane * 8;
          Bh[g][m] = *(const bf16x8*)&wpack[bidx];
          Bl[g][m] = *(const bf16x8*)&wpack[bidx + 512];
        }
      }
      #pragma unroll
      for (int g = 0; g < 3; ++g) {
        acc[g][0] = __builtin_amdgcn_mfma_f32_16x16x32_bf16(aXh[c], Bh[g][0], acc[g][0], 0, 0, 0);
        acc[g][1] = __builtin_amdgcn_mfma_f32_16x16x32_bf16(aHh[c], Bh[g][1], acc[g][1], 0, 0, 0);
      }
      #pragma unroll
      for (int g = 0; g < 3; ++g) {
        acc[g][0] = __builtin_amdgcn_mfma_f32_16x16x32_bf16(aXh[c], Bl[g][0], acc[g][0], 0, 0, 0);
        acc[g][1] = __builtin_amdgcn_mfma_f32_16x16x32_bf16(aHh[c], Bl[g][1], acc[g][1], 0, 0, 0);
      }
      #pragma unroll
      for (int g = 0; g < 3; ++g) {
        acc[g][0] = __builtin_amdgcn_mfma_f32_16x16x32_bf16(aXl[c], Bh[g][0], acc[g][0], 0, 0, 0);
        acc[g][1] = __builtin_amdgcn_mfma_f32_16x16x32_bf16(aHl[c], Bh[g][1], acc[g][1], 0, 0, 0);
      }
    }
    int j = t * 16 + nIdx;
    float biR = b_ih[j],       bhR = b_hh[j];
    float biZ = b_ih[128 + j], bhZ = b_hh[128 + j];
    float biN = b_ih[256 + j], bhN = b_hh[256 + j];
    #pragma unroll
    for (int i = 0; i < 4; ++i) {
      float gr = acc[0][0][i] + biR + acc[0][1][i] + bhR;
      float gz = acc[1][0][i] + biZ + acc[1][1][i] + bhZ;
      float r = 1.f / (1.f + expf(-gr));
      float z = 1.f / (1.f + expf(-gz));
      float nct = tanhf(acc[2][0][i] + biN + r * (acc[2][1][i] + bhN));
      int lrow = wave * 16 + quad * 4 + i;
      float h0 = bf16_to_f(Hhi[lrow * GPAD + j]) + bf16_to_f(Hlo[lrow * GPAD + j]);
      float h = (1.f - z) * nct + z * h0;
      if (!zm[i]) h = 0.f;
      Hbuf[(size_t)grows[i] * 128 + j] = h;
    }
  }
}

// ------------------------------------------------------------------
// K5 v2: attention + h_read, wave-parallel softmax.  grid=512, block=128
#define HLS 129
__global__ void k_attn(const float* __restrict__ Hbuf, const float* __restrict__ ws,
                       const float* __restrict__ b_read, const int* __restrict__ info,
                       float* __restrict__ hread) {
  int b = blockIdx.x, tid = threadIdx.x;
  __shared__ float Hl[SEQL * HLS];
  __shared__ float sc[128];
  __shared__ float hl[128];
  __shared__ float att[SEQL];
  __shared__ float loc[128];
  __shared__ float redm[2], reds[2];
  int nn = info[b * 4 + 3], li = info[b * 4 + 1];
  for (int e = tid; e < SEQL * 128; e += 128) {
    int r = e >> 7, k = e & 127;
    Hl[r * HLS + k] = Hbuf[((size_t)(b * SEQL + r)) * DIM + k];
  }
  __syncthreads();
  hl[tid] = Hl[li * HLS + tid];
  __syncthreads();
  float scr = NEGV;
  if (tid < nn) {
    float s = 0.f;
    for (int k = 0; k < 128; ++k) s += Hl[tid * HLS + k] * hl[k];
    scr = s;
  }
  sc[tid] = scr;
  __syncthreads();
  // parallel max over 128 entries (sc[tid>=nn] == NEGV)
  float m = sc[tid];
  #pragma unroll
  for (int o = 32; o >= 1; o >>= 1) m = fmaxf(m, __shfl_xor(m, o, 64));
  if ((tid & 63) == 0) redm[tid >> 6] = m;
  __syncthreads();
  m = fmaxf(redm[0], redm[1]);
  float e = (tid < SEQL) ? expf(sc[tid] - m) : 0.f;
  float s = e;
  #pragma unroll
  for (int o = 32; o >= 1; o >>= 1) s += __shfl_xor(s, o, 64);
  if ((tid & 63) == 0) reds[tid >> 6] = s;
  __syncthreads();
  float inv = 1.f / (reds[0] + reds[1]);
  if (tid < SEQL) att[tid] = e * inv;
  __syncthreads();
  float lv = 0.f;
  for (int n = 0; n < SEQL; ++n) lv = fmaf(att[n], Hl[n * HLS + tid], lv);
  loc[tid] = lv;
  __syncthreads();
  const float* WrT = ws + OFF_WREADT;
  float acc = b_read[tid];
  for (int j = 0; j < 128; ++j) acc = fmaf(WrT[j * 128 + tid], hl[j], acc);
  for (int j = 0; j < 128; ++j) acc = fmaf(WrT[(128 + j) * 128 + tid], loc[j], acc);
  hread[b * 128 + tid] = tanhf(acc);
}

// ------------------------------------------------------------------
// K5b: pack hread (512x128) into bf16 hi/lo frags (B-role for k_out).
// apack layout: [btile(32)][kc(4)][hi/lo(2)][lane(64)][8 halves]
__global__ __launch_bounds__(256) void k_packA(
    const float* __restrict__ hread, unsigned short* __restrict__ apack) {
  int idx = blockIdx.x * 256 + threadIdx.x;     // 8192 slots total
  if (idx >= 8192) return;
  int lane = idx & 63;
  int kc = (idx >> 6) & 3;
  int mt = idx >> 8;
  int quad = lane >> 4, rr = lane & 15;
  int row = mt * 16 + rr;
  int kbase = kc * 32 + quad * 8;
  const float4* hr4 = (const float4*)(hread + row * 128 + kbase);
  float4 v0 = hr4[0], v1 = hr4[1];
  float vs[8] = {v0.x, v0.y, v0.z, v0.w, v1.x, v1.y, v1.z, v1.w};
  bf16x8 hi, lo;
  #pragma unroll
  for (int j = 0; j < 8; ++j) {
    unsigned short h = bf16_rne(vs[j]);
    hi[j] = (short)h;
    lo[j] = (short)bf16_rne(vs[j] - bf16_to_f(h));
  }
  size_t base = ((size_t)(mt * 4 + kc) * 2) * 512 + (size_t)lane * 8;
  *(bf16x8*)&apack[base] = hi;
  *(bf16x8*)&apack[base + 512] = lo;
}

// ------------------------------------------------------------------
// K5c: pack emb (100000x128, zero-pad to 100032) into bf16 hi/lo frags
// (A-role for k_out).  epack: [ittile(6252)][kc(4)][hi/lo(2)][lane(64)][8]
// grid=6252, block=256 (one it-tile per block).
__global__ __launch_bounds__(256) void k_epack(
    const float* __restrict__ emb, unsigned short* __restrict__ epack) {
  int idx = blockIdx.x * 256 + threadIdx.x;
  int lane = idx & 63;
  int kc = (idx >> 6) & 3;
  int it = idx >> 8;
  int quad = lane >> 4, rr = lane & 15;
  int row = it * 16 + rr;
  int kbase = kc * 32 + quad * 8;
  float4 v0 = {0.f, 0.f, 0.f, 0.f}, v1 = {0.f, 0.f, 0.f, 0.f};
  if (row < NITEMS) {
    const float4* p = (const float4*)(emb + (size_t)row * 128 + kbase);
    v0 = p[0]; v1 = p[1];
  }
  float vs[8] = {v0.x, v0.y, v0.z, v0.w, v1.x, v1.y, v1.z, v1.w};
  bf16x8 hi, lo;
  #pragma unroll
  for (int j = 0; j < 8; ++j) {
    unsigned short h = bf16_rne(vs[j]);
    hi[j] = (short)h;
    lo[j] = (short)bf16_rne(vs[j] - bf16_to_f(h));
  }
  size_t base = ((size_t)(it * 4 + kc) * 2) * 512 + (size_t)lane * 8;
  *(bf16x8*)&epack[base] = hi;
  *(bf16x8*)&epack[base + 512] = lo;
}

// ------------------------------------------------------------------
// K6 v4: out = h_read @ emb^T, operand-swapped (C = emb_tile @ hread^T so
// row=item, col=batch -> float4 stores).  Pure-register kernel: no LDS,
// no syncthreads; frags loaded directly from epack/apack (L2/L3 resident).
// grid (4, 1563), block 256 = 4 waves.  Wave: 2 batch-tiles x 4 item-tiles.
__global__ __launch_bounds__(256) void k_out(
    const unsigned short* __restrict__ epack, const unsigned short* __restrict__ apack,
    const int* __restrict__ info, float* __restrict__ out) {
  int tid = threadIdx.x;
  int wave = tid >> 6, lane = tid & 63;
  int quad = lane >> 4, nIdx = lane & 15;
  int b0   = blockIdx.x * 128;
  int itt0 = blockIdx.y * 4;              // item-tile base (of 6252)
  int btg0 = blockIdx.x * 8 + wave * 2;   // batch-tile base (of 32)

  // B-frags: hread (packed), 2 batch-tiles x 4 k-chunks x hi/lo
  bf16x8 bh[2][4], bl[2][4];
  #pragma unroll
  for (int m2 = 0; m2 < 2; ++m2)
    #pragma unroll
    for (int kc = 0; kc < 4; ++kc) {
      size_t base = ((size_t)((btg0 + m2) * 4 + kc) * 2) * 512 + (size_t)lane * 8;
      bh[m2][kc] = *(const bf16x8*)&apack[base];
      bl[m2][kc] = *(const bf16x8*)&apack[base + 512];
    }

  f32x4 acc[4][2];
  #pragma unroll
  for (int it = 0; it < 4; ++it)
    #pragma unroll
    for (int m2 = 0; m2 < 2; ++m2) acc[it][m2] = (f32x4){0.f, 0.f, 0.f, 0.f};

  #pragma unroll
  for (int it = 0; it < 4; ++it) {
    #pragma unroll
    for (int kc = 0; kc < 4; ++kc) {
      size_t abase = ((size_t)((itt0 + it) * 4 + kc) * 2) * 512 + (size_t)lane * 8;
      bf16x8 Ah = *(const bf16x8*)&epack[abase];
      bf16x8 Al = *(const bf16x8*)&epack[abase + 512];
      acc[it][0] = __builtin_amdgcn_mfma_f32_16x16x32_bf16(Ah, bh[0][kc], acc[it][0], 0, 0, 0);
      acc[it][1] = __builtin_amdgcn_mfma_f32_16x16x32_bf16(Ah, bh[1][kc], acc[it][1], 0, 0, 0);
      acc[it][0] = __builtin_amdgcn_mfma_f32_16x16x32_bf16(Al, bh[0][kc], acc[it][0], 0, 0, 0);
      acc[it][1] = __builtin_amdgcn_mfma_f32_16x16x32_bf16(Al, bh[1][kc], acc[it][1], 0, 0, 0);
      acc[it][0] = __builtin_amdgcn_mfma_f32_16x16x32_bf16(Ah, bl[0][kc], acc[it][0], 0, 0, 0);
      acc[it][1] = __builtin_amdgcn_mfma_f32_16x16x32_bf16(Ah, bl[1][kc], acc[it][1], 0, 0, 0);
    }
  }

  // epilogue: C[item][b]; col=lane&15 -> b-in-tile, row=quad*4+i -> item-in-tile
  #pragma unroll
  for (int m2 = 0; m2 < 2; ++m2) {
    int b = b0 + (wave * 2 + m2) * 16 + nIdx;
    int flag = info[b * 4 + 2];
    #pragma unroll
    for (int it = 0; it < 4; ++it) {
      int ib = (itt0 + it) * 16 + quad * 4;    // base item of this float4
      if (ib < NITEMS) {                       // NITEMS%4==0 -> whole float4 in/out
        float4 v;
        if (flag) {
          v.x = acc[it][m2][0]; v.y = acc[it][m2][1];
          v.z = acc[it][m2][2]; v.w = acc[it][m2][3];
        } else {
          v.x = (ib == 0) ? 0.f : NEGV; v.y = NEGV; v.z = NEGV; v.w = NEGV;
        }
        *(float4*)&out[(size_t)b * NITEMS + ib] = v;
      }
    }
  }
}

// ------------------------------------------------------------------
extern "C" void kernel_launch(void* const* d_in, const int* in_sizes, int n_in,
                              void* d_out, int out_size, void* d_ws, size_t ws_size,
                              hipStream_t stream) {
  const int*   x      = (const int*)d_in[0];
  const float* emb    = (const float*)d_in[2];
  const float* W_in   = (const float*)d_in[3];
  const float* W_out  = (const float*)d_in[4];
  const float* w_ih   = (const float*)d_in[5];
  const float* w_hh   = (const float*)d_in[6];
  const float* b_ih   = (const float*)d_in[7];
  const float* b_hh   = (const float*)d_in[8];
  const float* W_read = (const float*)d_in[9];
  const float* b_read = (const float*)d_in[10];
  float* ws  = (float*)d_ws;
  int*   wsi = (int*)d_ws;
  unsigned short* wpack  = (unsigned short*)(ws + OFF_WPACK_F);
  unsigned short* wpack2 = (unsigned short*)ws;
  unsigned short* apack  = (unsigned short*)(ws + OFF_XIN);      // xin dead after k_gru
  unsigned short* epack  = (unsigned short*)(ws + OFF_EPACK_F);  // xin+hout dead after k_attn
  float* out = (float*)d_out;

  k_prep<<<384, 256, 0, stream>>>(w_ih, w_hh, W_in, W_out, W_read, ws, wpack);
  k_build<<<BATCH, 128, 0, stream>>>(x, wsi + OFF_NODES_I, ws + OFF_DEG,
                                     wsi + OFF_SRC_I, wsi + OFF_DST_I, wsi + OFF_INFO_I);
  k_gemm_inout<<<1600, 128, 0, stream>>>(emb, wpack2, wsi + OFF_NODES_I,
                                         ws + OFF_XIN, ws + OFF_HOUT);
  k_scatter<<<BATCH, 128, 0, stream>>>(ws + OFF_HOUT, ws + OFF_XIN, ws + OFF_DEG,
                                       wsi + OFF_SRC_I, wsi + OFF_DST_I, wsi + OFF_INFO_I);
  k_gru<<<1600, 128, 0, stream>>>(emb, wsi + OFF_NODES_I, wpack, ws + OFF_XIN,
                                  b_ih, b_hh, wsi + OFF_INFO_I, ws + OFF_HOUT);
  k_attn<<<BATCH, 128, 0, stream>>>(ws + OFF_HOUT, ws, b_read, wsi + OFF_INFO_I,
                                    ws + OFF_HREAD);
  k_epack<<<6252, 256, 0, stream>>>(emb, epack);
  k_packA<<<32, 256, 0, stream>>>(ws + OFF_HREAD, apack);
  k_out<<<dim3(4, 1563), 256, 0, stream>>>(epack, apack, wsi + OFF_INFO_I, out);
}